// Round 2
// baseline (55.775 us; speedup 1.0000x reference)
//
#include <hip/hip_runtime.h>

// TrigoLinear: out[b,o] = sum_i w_out[o,i]*sin(x[b,i]*w_sin[o,i]+b_sin[o,i]) + b_out[o]
// B=2048, I=256, O=512. Compute-bound: 268M hardware v_sin ops.
//
// R2 changes vs R1 (53us, VALUBusy 63%, 4 waves/SIMD):
//  - prep kernel: deinterleave weight streams + pre-scale by 1/2pi into d_ws
//    -> inner chain is exactly fma + v_sin + fma (12 cy/wave-elem issue)
//  - drop v_fract: v_sin_f32 valid to +-256 revolutions, |arg| < 0.5 rev here
//  - ITILE 128->64 (LDS 16.6KB), OBLOCK 16->8, grid 2048 -> 8 blocks/CU,
//    8 waves/SIMD for latency hiding of s_load/ds_read/sin chains.

#define B_SZ 2048
#define I_SZ 256
#define O_SZ 512
#define BTILE 64
#define ITILE 64
#define OBLOCK 8  // o's per block (4 waves x 2)
#define NOO 2     // o's per wave (wave-uniform -> scalar loads)

static constexpr float kInv2Pi = 0.15915494309189535f;

__global__ __launch_bounds__(256) void prep_kernel(
    const float* __restrict__ w, const float* __restrict__ bias,
    float* __restrict__ A, float* __restrict__ Bm, float* __restrict__ C) {
  const int o = blockIdx.x;   // 512
  const int i = threadIdx.x;  // 256
  const float2 wp = *reinterpret_cast<const float2*>(&w[o * (2 * I_SZ) + 2 * i]);
  A[o * I_SZ + i] = wp.y * kInv2Pi;              // w_sin / 2pi
  Bm[o * I_SZ + i] = wp.x;                       // w_out
  C[o * I_SZ + i] = bias[o * (I_SZ + 1) + i] * kInv2Pi;  // b_sin / 2pi
}

template <bool PREPPED>
__global__ __launch_bounds__(256, 8) void TrigoLinear_kernel(
    const float* __restrict__ x, const float* __restrict__ A,
    const float* __restrict__ Bm, const float* __restrict__ C,
    const float* __restrict__ w, const float* __restrict__ bias,
    float* __restrict__ out) {
  __shared__ float xT[ITILE][BTILE + 1];  // 16640 B; +1 pad -> conflict-free

  const int tid = threadIdx.x;
  const int lane = tid & 63;
  const int wave = __builtin_amdgcn_readfirstlane(tid >> 6);

  const int btile = blockIdx.x & 31;   // 32 b-tiles
  const int oblock = blockIdx.x >> 5;  // 64 o-blocks
  const int b0 = btile * BTILE;
  const int o_base = oblock * OBLOCK + wave * NOO;  // wave-uniform

  float acc[NOO] = {0.f, 0.f};

  for (int it = 0; it < I_SZ / ITILE; ++it) {  // 4 tiles of 64
    __syncthreads();
    // stage x[b0..b0+63][it*64..+63] transposed. 4096 elems = 1024 float4.
    // 16 consecutive lanes read one 256B row segment -> coalesced.
#pragma unroll
    for (int c = 0; c < 4; ++c) {
      const int idx = tid + c * 256;   // float4 index in tile
      const int row = idx >> 4;        // 16 float4 per 64-elem row
      const int col = (idx & 15) * 4;
      float4 v = *reinterpret_cast<const float4*>(
          &x[(b0 + row) * I_SZ + it * ITILE + col]);
      if (!PREPPED) {  // fallback: pre-scale x by 1/2pi at staging
        v.x *= kInv2Pi; v.y *= kInv2Pi; v.z *= kInv2Pi; v.w *= kInv2Pi;
      }
      xT[col + 0][row] = v.x;
      xT[col + 1][row] = v.y;
      xT[col + 2][row] = v.z;
      xT[col + 3][row] = v.w;
    }
    __syncthreads();

#pragma unroll 8
    for (int i = 0; i < ITILE; ++i) {
      const float xs = xT[i][lane];  // conflict-free ds_read_b32
      const int ig = it * ITILE + i;
#pragma unroll
      for (int oo = 0; oo < NOO; ++oo) {
        const int o = o_base + oo;  // wave-uniform -> s_load streams
        if (PREPPED) {
          const float a = A[o * I_SZ + ig];   // w_sin/2pi
          const float bo = Bm[o * I_SZ + ig]; // w_out
          const float c = C[o * I_SZ + ig];   // b_sin/2pi
          const float rev = __builtin_fmaf(xs, a, c);     // revolutions
          const float sv = __builtin_amdgcn_sinf(rev);    // v_sin_f32
          acc[oo] = __builtin_fmaf(sv, bo, acc[oo]);
        } else {
          const float wov = w[o * (2 * I_SZ) + 2 * ig];
          const float wsv = w[o * (2 * I_SZ) + 2 * ig + 1];
          const float bsv = bias[o * (I_SZ + 1) + ig];
          const float t = xs * wsv;  // xs pre-scaled
          const float rev = __builtin_fmaf(bsv, kInv2Pi, t);
          const float sv = __builtin_amdgcn_sinf(rev);
          acc[oo] = __builtin_fmaf(sv, wov, acc[oo]);
        }
      }
    }
  }

  const int b = b0 + lane;
#pragma unroll
  for (int oo = 0; oo < NOO; ++oo) {
    const int o = o_base + oo;
    out[b * O_SZ + o] = acc[oo] + bias[o * (I_SZ + 1) + I_SZ];
  }
}

extern "C" void kernel_launch(void* const* d_in, const int* in_sizes, int n_in,
                              void* d_out, int out_size, void* d_ws, size_t ws_size,
                              hipStream_t stream) {
  const float* x = (const float*)d_in[0];     // (2048, 256) f32
  const float* w = (const float*)d_in[1];     // (512, 256, 2) f32
  const float* bias = (const float*)d_in[2];  // (512, 257) f32
  float* out = (float*)d_out;                 // (2048, 512) f32

  const int grid = (B_SZ / BTILE) * (O_SZ / OBLOCK);  // 32 * 64 = 2048
  const size_t need = (size_t)3 * O_SZ * I_SZ * sizeof(float);  // 1.5 MB

  if (ws_size >= need) {
    float* A = (float*)d_ws;
    float* Bm = A + O_SZ * I_SZ;
    float* C = Bm + O_SZ * I_SZ;
    prep_kernel<<<dim3(O_SZ), dim3(I_SZ), 0, stream>>>(w, bias, A, Bm, C);
    TrigoLinear_kernel<true><<<dim3(grid), dim3(256), 0, stream>>>(
        x, A, Bm, C, w, bias, out);
  } else {
    TrigoLinear_kernel<false><<<dim3(grid), dim3(256), 0, stream>>>(
        x, nullptr, nullptr, nullptr, w, bias, out);
  }
}